// Round 9
// baseline (301.779 us; speedup 1.0000x reference)
//
#include <hip/hip_runtime.h>
#include <math.h>

#define NATOMS   1025
#define GSTRIDE  1040               // padded row stride (floats)
#define GELEMS   (1025*GSTRIDE)
#define NNZ      32
#define NBATCH   64
#define REGL     0.0067153485f      // softplus(-5) in fp32

// DPP cross-lane helpers (VALU-latency, no LDS). old=0, bound_ctrl=false ->
// invalid source lanes contribute 0 (safe: max over non-negatives / sum).
#define DPPF(x, ctrl) __int_as_float(__builtin_amdgcn_update_dpp(0, __float_as_int(x), (ctrl), 0xF, 0xF, false))

__device__ __forceinline__ float wave_max64(float x) {
    x = fmaxf(x, DPPF(x, 0x111));   // row_shr:1
    x = fmaxf(x, DPPF(x, 0x112));   // row_shr:2
    x = fmaxf(x, DPPF(x, 0x114));   // row_shr:4
    x = fmaxf(x, DPPF(x, 0x118));   // row_shr:8
    x = fmaxf(x, DPPF(x, 0x142));   // row_bcast:15
    x = fmaxf(x, DPPF(x, 0x143));   // row_bcast:31
    return __int_as_float(__builtin_amdgcn_readlane(__float_as_int(x), 63));
}
__device__ __forceinline__ float wave_sum64(float x) {
    x += DPPF(x, 0x111);
    x += DPPF(x, 0x112);
    x += DPPF(x, 0x114);
    x += DPPF(x, 0x118);
    x += DPPF(x, 0x142);
    x += DPPF(x, 0x143);
    return __int_as_float(__builtin_amdgcn_readlane(__float_as_int(x), 63));
}

// ---------------------------------------------------------------------------
// fused gram+projy. blockIdx.z < nsplit: gram (triangular bx<=by, 128x128 tile,
// 8x8/thread, split-K partials in Gp[z]). blockIdx.z == nsplit: projy.
// Diagonal tiles (bx==by) are computed FULL (both triangles within the tile).
// ---------------------------------------------------------------------------
__global__ __launch_bounds__(256)
void gramprojy_kernel(const float* __restrict__ X0, const float* __restrict__ y,
                      float* __restrict__ Gout, float* __restrict__ PY,
                      int kLen, int nsplit) {
    __shared__ float lds[8192];
    const int tid = threadIdx.x;

    if ((int)blockIdx.z < nsplit) {
        // ================= gram role =================
        const int bx = blockIdx.x, by = blockIdx.y, bz = blockIdx.z;
        if (by < bx) return;
        float* As = lds;            // [32][128]
        float* Bs = lds + 4096;     // [32][128]
        const int a0 = bx * 128, b0 = by * 128;
        float* __restrict__ Gp = Gout + (size_t)bz * GELEMS;
        const int tx = tid & 15;
        const int ty = tid >> 4;
        const int lr = tid >> 5;
        const int lc = (tid & 31) * 4;
        const bool aIn = (a0 + 128) <= 1024;
        const bool bIn = (b0 + 128) <= 1024;

        float acc[8][8];
#pragma unroll
        for (int m = 0; m < 8; ++m)
#pragma unroll
            for (int n = 0; n < 8; ++n) acc[m][n] = 0.0f;

        const int kBase = bz * kLen;
        for (int kc = 0; kc < kLen; kc += 32) {
#pragma unroll
            for (int rr = 0; rr < 4; ++rr) {
                const int r = lr + rr * 8;
                const int l = kBase + kc + r;
                if (aIn) {
                    *(float4*)&As[r * 128 + lc] = *(const float4*)&X0[(size_t)l * 1024 + a0 + lc];
                } else {
#pragma unroll
                    for (int k = 0; k < 4; ++k) {
                        const int col = a0 + lc + k;
                        As[r * 128 + lc + k] = (col < 1024) ? X0[(size_t)l * 1024 + col]
                                                            : (col == 1024 ? 1.0f : 0.0f);
                    }
                }
                if (bIn) {
                    *(float4*)&Bs[r * 128 + lc] = *(const float4*)&X0[(size_t)l * 1024 + b0 + lc];
                } else {
#pragma unroll
                    for (int k = 0; k < 4; ++k) {
                        const int col = b0 + lc + k;
                        Bs[r * 128 + lc + k] = (col < 1024) ? X0[(size_t)l * 1024 + col]
                                                            : (col == 1024 ? 1.0f : 0.0f);
                    }
                }
            }
            __syncthreads();
#pragma unroll 8
            for (int l = 0; l < 32; ++l) {
                float4 a01 = *(const float4*)&As[l * 128 + ty * 8];
                float4 a23 = *(const float4*)&As[l * 128 + ty * 8 + 4];
                float4 bA  = *(const float4*)&Bs[l * 128 + tx * 4];
                float4 bB  = *(const float4*)&Bs[l * 128 + 64 + tx * 4];
                float am[8] = {a01.x, a01.y, a01.z, a01.w, a23.x, a23.y, a23.z, a23.w};
                float bn[8] = {bA.x, bA.y, bA.z, bA.w, bB.x, bB.y, bB.z, bB.w};
#pragma unroll
                for (int m = 0; m < 8; ++m)
#pragma unroll
                    for (int n = 0; n < 8; ++n)
                        acc[m][n] += am[m] * bn[n];
            }
            __syncthreads();
        }

#pragma unroll
        for (int m = 0; m < 8; ++m) {
            const int a = a0 + ty * 8 + m;
            if (a >= NATOMS) continue;
            const int bAc = b0 + tx * 4;
            const int bBc = b0 + 64 + tx * 4;
            if (bAc < GSTRIDE) {
                *(float4*)&Gp[(size_t)a * GSTRIDE + bAc] =
                    make_float4(acc[m][0], acc[m][1], acc[m][2], acc[m][3]);
            }
            if (bBc < GSTRIDE) {
                *(float4*)&Gp[(size_t)a * GSTRIDE + bBc] =
                    make_float4(acc[m][4], acc[m][5], acc[m][6], acc[m][7]);
            }
        }
    } else {
        // ================= projy role =================
        const int pw = blockIdx.y * 9 + blockIdx.x;
        if (pw >= 68) return;
        const int a0 = (pw % 17) * 64;
        const int b0 = (pw / 17) * 16;
        float* Ds = lds;            // [32][64]
        float* Ys = lds + 2048;     // [32][17]
        const int tx = tid & 15;
        const int ty = tid >> 4;
        const bool aIn = (a0 + 64) <= 1024;

        float acc[4] = {0.0f, 0.0f, 0.0f, 0.0f};

        for (int kc = 0; kc < 1024; kc += 32) {
            {
                const int r  = tid >> 4;
                const int c4 = (tid & 15) * 4;
#pragma unroll
                for (int rr = 0; rr < 2; ++rr) {
                    const int row = r + rr * 16;
                    const int l = kc + row;
                    if (aIn) {
                        *(float4*)&Ds[row * 64 + c4] = *(const float4*)&X0[(size_t)l * 1024 + a0 + c4];
                    } else {
#pragma unroll
                        for (int k = 0; k < 4; ++k) {
                            const int col = a0 + c4 + k;
                            Ds[row * 64 + c4 + k] = (col < 1024) ? X0[(size_t)l * 1024 + col]
                                                                 : (col == 1024 ? 1.0f : 0.0f);
                        }
                    }
                }
            }
            for (int e = tid; e < 512; e += 256) {
                const int l = e & 31, bb = e >> 5;
                Ys[l * 17 + bb] = y[(size_t)(b0 + bb) * 1024 + kc + l];
            }
            __syncthreads();
#pragma unroll 8
            for (int l = 0; l < 32; ++l) {
                const float yv = Ys[l * 17 + ty];
                float4 dv = *(const float4*)&Ds[l * 64 + tx * 4];
                acc[0] += yv * dv.x; acc[1] += yv * dv.y;
                acc[2] += yv * dv.z; acc[3] += yv * dv.w;
            }
            __syncthreads();
        }
        const int a = a0 + tx * 4;
        if (a < GSTRIDE) {
            *(float4*)&PY[(size_t)(b0 + ty) * GSTRIDE + a] =
                make_float4(acc[0], acc[1], acc[2], acc[3]);
        }
    }
}

// ---------------------------------------------------------------------------
// omp: one wg/batch, 512 threads (8 waves), 2 barriers/iter.
// Thread tid owns atoms tid and tid+512 (tid 511 also atom 1024) -> stride-1
// conflict-free LDS access in proj/stage. Reads Gram rows directly from the
// split-K partials Gp with triangular addressing (no combine kernel):
//   G[sel][a] = sum_z Gp[z][min-tile-major], diag likewise at init.
// Staging loads issue right after the winner and complete UNDER the solve.
// rowsLds[i] staged AFTER the incremental proj update (R7 lesson).
// ---------------------------------------------------------------------------
__global__ __launch_bounds__(512)
void omp_kernel(const float* __restrict__ Gp, const float* __restrict__ PY,
                int nsplit, int* __restrict__ idxOut, float* __restrict__ wOut) {
    __shared__ float rowsLds[NNZ][GSTRIDE];   // 133,120 B, zero-init
    __shared__ float pyLds[1040];
    __shared__ float diagLds[1040];
    __shared__ float Ainv[32][33];
    __shared__ float wv[32], rhs[32], uvb[32];
    __shared__ int   selIdx[32];
    __shared__ float redV[8];
    __shared__ int   redI[8];
    __shared__ float sc_dinv;

    const int b = blockIdx.x, tid = threadIdx.x;
    const int lane = tid & 63, wid = tid >> 6;

    // ---- init: zero padded state; load py; build diag from partials
    {
        float4 z4 = make_float4(0.f, 0.f, 0.f, 0.f);
        float4* rz = (float4*)rowsLds;
        for (int u = tid; u < NNZ * GSTRIDE / 4; u += 512) rz[u] = z4;
        if (tid < 32) { wv[tid] = 0.f; rhs[tid] = 0.f; uvb[tid] = 0.f; }
        for (int u = tid; u < 32 * 33; u += 512) ((float*)Ainv)[u] = 0.f;
        const float* pyg = PY + (size_t)b * GSTRIDE;
        for (int u = tid; u < 1040; u += 512) pyLds[u] = pyg[u];
        float d0 = 0.f, d1 = 0.f, d2 = 0.f;
        for (int z = 0; z < nsplit; ++z) {
            const float* gz = Gp + (size_t)z * GELEMS;
            d0 += gz[(size_t)tid * GSTRIDE + tid];
            d1 += gz[(size_t)(tid + 512) * GSTRIDE + (tid + 512)];
            if (tid == 511) d2 += gz[(size_t)1024 * GSTRIDE + 1024];
        }
        diagLds[tid] = d0;
        diagLds[tid + 512] = d1;
        if (tid == 511) diagLds[1024] = d2;
    }
    __syncthreads();

    // ---- registers: proj for atoms tid, tid+512 (+1024 on tid 511)
    float p0 = pyLds[tid], p1 = pyLds[tid + 512];
    float p2 = (tid == 511) ? pyLds[1024] : 0.0f;

    // ---- prologue argmax on |py|
    {
        float best = fabsf(p0); int bidx = tid;
        { float v = fabsf(p1); if (v > best) { best = v; bidx = tid + 512; } }
        if (tid == 511) { float v = fabsf(p2); if (v > best) { best = v; bidx = 1024; } }
        const float wmax = wave_max64(best);
        const unsigned long long mask = __ballot(best == wmax);
        const int fl = __ffsll((unsigned long long)mask) - 1;
        const int widx = __builtin_amdgcn_readlane(bidx, fl);
        if (lane == 0) { redV[wid] = wmax; redI[wid] = widx; }
    }
    __syncthreads();                                         // barA

    for (int i = 0; i < NNZ; ++i) {
        // ---- winner, replicated identically on all threads
        float bv_ = redV[0]; int sel = redI[0];
#pragma unroll
        for (int q = 1; q < 8; ++q) {
            if (redV[q] > bv_ || (redV[q] == bv_ && redI[q] < sel)) {
                bv_ = redV[q]; sel = redI[q];
            }
        }
        const float pysel = pyLds[sel];

        // ---- issue G-row loads NOW from partials (complete under the solve)
        float r0 = 0.f, r1 = 0.f, r2 = 0.f;
        if (i < NNZ - 1) {
            const int st = sel >> 7;
            {
                const int a = tid;
                const size_t off = (st <= (a >> 7)) ? ((size_t)sel * GSTRIDE + a)
                                                    : ((size_t)a * GSTRIDE + sel);
                for (int z = 0; z < nsplit; ++z) r0 += Gp[(size_t)z * GELEMS + off];
            }
            {
                const int a = tid + 512;
                const size_t off = (st <= (a >> 7)) ? ((size_t)sel * GSTRIDE + a)
                                                    : ((size_t)a * GSTRIDE + sel);
                for (int z = 0; z < nsplit; ++z) r1 += Gp[(size_t)z * GELEMS + off];
            }
            if (tid == 511) {
                const size_t off = (size_t)sel * GSTRIDE + 1024;   // tile(1024)=8 >= st
                for (int z = 0; z < nsplit; ++z) r2 += Gp[(size_t)z * GELEMS + off];
            }
        }

        // ---- solve (wave 0): border from rowsLds columns (rows j<i only)
        if (wid == 0) {
            float bvl = 0.0f, rl = 0.0f;
            if (lane < 32) { bvl = rowsLds[lane][sel]; rl = rhs[lane]; }
            const int lr_ = lane & 31;
            float u0 = 0.f, u1 = 0.f, u2 = 0.f, u3 = 0.f;
#pragma unroll
            for (int m = 0; m < 32; m += 4) {            // rows >= i are 0
                u0 = fmaf(Ainv[lr_][m + 0], rowsLds[m + 0][sel], u0);
                u1 = fmaf(Ainv[lr_][m + 1], rowsLds[m + 1][sel], u1);
                u2 = fmaf(Ainv[lr_][m + 2], rowsLds[m + 2][sel], u2);
                u3 = fmaf(Ainv[lr_][m + 3], rowsLds[m + 3][sel], u3);
            }
            const float uacc = (u0 + u1) + (u2 + u3);
            const float t = wave_sum64(bvl * uacc);      // lanes>=32 contribute 0
            const float s = wave_sum64(rl * uacc);
            const float dinv = 1.0f / (diagLds[sel] + REGL - t);
            const float beta = dinv * (pysel - s);
            if (lane < 32) {
                uvb[lane] = (lane == i) ? -1.0f : uacc;
                wv[lane]  = (lane == i) ? beta  : wv[lane] - uacc * beta;
            }
            if (lane == 0) { selIdx[i] = sel; rhs[i] = pysel; sc_dinv = dinv; }
        }
        __syncthreads();                                     // barB
        if (i == NNZ - 1) break;

        // ---- deferred rank-1 Ainv update (2 elems/thread, exact cover)
        {
            const float dcur = sc_dinv;
            const int e0 = 2 * tid, j0 = e0 >> 5, k0 = e0 & 31;
            Ainv[j0][k0] = fmaf(uvb[j0] * uvb[k0], dcur, Ainv[j0][k0]);
            const int e1 = 2 * tid + 1, j1 = e1 >> 5, k1 = e1 & 31;
            Ainv[j1][k1] = fmaf(uvb[j1] * uvb[k1], dcur, Ainv[j1][k1]);
        }

        // ---- incremental proj update: p += beta * sum_{j<=i} uvb[j]*rows[j]
        //      j=i term ONLY via registers (uvb[i] = -1); rowsLds[i] still 0.
        const float beta = wv[i];
        float z0 = -r0, z1 = -r1, z2 = -r2;
        for (int jb = 0; jb < NNZ; jb += 8) {
            if (jb >= i) break;
#pragma unroll
            for (int jj = 0; jj < 8; ++jj) {
                const int j = jb + jj;                   // j >= i terms are 0
                const float uj = uvb[j];
                z0 = fmaf(uj, rowsLds[j][tid],       z0);
                z1 = fmaf(uj, rowsLds[j][tid + 512], z1);
                if (tid == 511) z2 = fmaf(uj, rowsLds[j][1024], z2);
            }
        }
        p0 = fmaf(beta, z0, p0);
        p1 = fmaf(beta, z1, p1);
        if (tid == 511) p2 = fmaf(beta, z2, p2);

        // ---- NOW stage row i into LDS (after proj reads; before barA)
        rowsLds[i][tid]       = r0;
        rowsLds[i][tid + 512] = r1;
        if (tid == 511) rowsLds[i][1024] = r2;

        // ---- abs-argmax
        {
            float best = fabsf(p0); int bidx = tid;
            { float v = fabsf(p1); if (v > best) { best = v; bidx = tid + 512; } }
            if (tid == 511) { float v = fabsf(p2); if (v > best) { best = v; bidx = 1024; } }
            const float wmax = wave_max64(best);
            const unsigned long long mask = __ballot(best == wmax);
            const int fl = __ffsll((unsigned long long)mask) - 1;
            const int widx = __builtin_amdgcn_readlane(bidx, fl);
            if (lane == 0) { redV[wid] = wmax; redI[wid] = widx; }
        }
        __syncthreads();                                     // barA
    }

    if (tid < NNZ) {
        idxOut[b * NNZ + tid] = selIdx[tid];
        wOut[b * NNZ + tid] = wv[tid];
    }
}

// ---------------------------------------------------------------------------
// recon (sparse): out[b][l] = sum_i X[b][l][widx_i]*wval_i + bias.
// W dup-semantics preserved via dense last-wins scatter then gather-and-zero;
// atom 1024 (ones column) redirected into the bias. Reads only the 32
// selected columns of X (~120 MB of lines vs 268 MB dense).
// ---------------------------------------------------------------------------
__global__ __launch_bounds__(256)
void recon_kernel(const float* __restrict__ X, const int* __restrict__ idxIn,
                  const float* __restrict__ wIn, float* __restrict__ out) {
    __shared__ float Wd[1025];
    __shared__ float wval[NNZ];
    __shared__ int   widx[NNZ];
    __shared__ float biasS;
    const int b = blockIdx.x >> 2, chunk = blockIdx.x & 3;
    const int tid = threadIdx.x;
    for (int u = tid; u < 1025; u += 256) Wd[u] = 0.0f;
    __syncthreads();
    if (tid == 0) {
#pragma unroll
        for (int i = 0; i < NNZ; ++i) Wd[idxIn[b * NNZ + i]] = wIn[b * NNZ + i];
        float bias = 0.0f;
#pragma unroll
        for (int i = 0; i < NNZ; ++i) {
            const int gi = idxIn[b * NNZ + i];
            const float v = Wd[gi];
            Wd[gi] = 0.0f;                       // dup i reads 0 second time
            const bool isOnes = (gi == 1024);
            if (isOnes) bias += v;
            widx[i] = isOnes ? 0 : gi;
            wval[i] = isOnes ? 0.0f : v;
        }
        biasS = bias;
    }
    __syncthreads();
    const int l = chunk * 256 + tid;
    const float* __restrict__ xr = X + (size_t)b * 1024 * 1024 + (size_t)l * 1024;
    float a0 = biasS, a1 = 0.f, a2 = 0.f, a3 = 0.f;
#pragma unroll
    for (int i = 0; i < NNZ; i += 4) {
        a0 = fmaf(xr[widx[i + 0]], wval[i + 0], a0);
        a1 = fmaf(xr[widx[i + 1]], wval[i + 1], a1);
        a2 = fmaf(xr[widx[i + 2]], wval[i + 2], a2);
        a3 = fmaf(xr[widx[i + 3]], wval[i + 3], a3);
    }
    out[(size_t)b * 1024 + l] = (a0 + a1) + (a2 + a3);
}

// ---------------------------------------------------------------------------
extern "C" void kernel_launch(void* const* d_in, const int* in_sizes, int n_in,
                              void* d_out, int out_size, void* d_ws, size_t ws_size,
                              hipStream_t stream) {
    const float* X = (const float*)d_in[0];
    const float* y = (const float*)d_in[1];
    float* out = (float*)d_out;
    float* ws = (float*)d_ws;

    const size_t need4 = ((size_t)GELEMS * 4 + 64 * GSTRIDE + NBATCH * NNZ * 2 + 64) * sizeof(float);
    const int nsplit = (ws_size >= need4) ? 4 : 1;
    const int kLen = 1024 / nsplit;

    float* Gp = ws;
    float* PY = ws + (size_t)GELEMS * nsplit;
    float* wOut = PY + (size_t)64 * GSTRIDE;
    int* idxOut = (int*)(wOut + NBATCH * NNZ);

    gramprojy_kernel<<<dim3(9, 9, nsplit + 1), 256, 0, stream>>>(X, y, Gp, PY, kLen, nsplit);
    omp_kernel<<<NBATCH, 512, 0, stream>>>(Gp, PY, nsplit, idxOut, wOut);
    recon_kernel<<<NBATCH * 4, 256, 0, stream>>>(X, idxOut, wOut, out);
}

// Round 10
// 221.230 us; speedup vs baseline: 1.3641x; 1.3641x over previous
//
#include <hip/hip_runtime.h>
#include <math.h>

#define NATOMS   1025
#define GSTRIDE  1040               // padded row stride (floats)
#define GELEMS   (1025*GSTRIDE)
#define NNZ      32
#define NBATCH   64
#define REGL     0.0067153485f      // softplus(-5) in fp32

// DPP cross-lane helpers (VALU-latency, no LDS). old=0, bound_ctrl=false ->
// invalid source lanes contribute 0 (safe: max over non-negatives / sum).
#define DPPF(x, ctrl) __int_as_float(__builtin_amdgcn_update_dpp(0, __float_as_int(x), (ctrl), 0xF, 0xF, false))

__device__ __forceinline__ float wave_max64(float x) {
    x = fmaxf(x, DPPF(x, 0x111));   // row_shr:1
    x = fmaxf(x, DPPF(x, 0x112));   // row_shr:2
    x = fmaxf(x, DPPF(x, 0x114));   // row_shr:4
    x = fmaxf(x, DPPF(x, 0x118));   // row_shr:8
    x = fmaxf(x, DPPF(x, 0x142));   // row_bcast:15
    x = fmaxf(x, DPPF(x, 0x143));   // row_bcast:31
    return __int_as_float(__builtin_amdgcn_readlane(__float_as_int(x), 63));
}
__device__ __forceinline__ float wave_sum64(float x) {
    x += DPPF(x, 0x111);
    x += DPPF(x, 0x112);
    x += DPPF(x, 0x114);
    x += DPPF(x, 0x118);
    x += DPPF(x, 0x142);
    x += DPPF(x, 0x143);
    return __int_as_float(__builtin_amdgcn_readlane(__float_as_int(x), 63));
}
__device__ __forceinline__ float readlane_f(float x, int l) {
    return __int_as_float(__builtin_amdgcn_readlane(__float_as_int(x), l));
}

// ---------------------------------------------------------------------------
// fused gram+projy. blockIdx.z < nsplit: gram (triangular bx<=by, 128x128 tile,
// 8x8/thread, split-K). blockIdx.z == nsplit: projy (64-atom x 16-batch tile).
// ---------------------------------------------------------------------------
__global__ __launch_bounds__(256)
void gramprojy_kernel(const float* __restrict__ X0, const float* __restrict__ y,
                      float* __restrict__ Gout, float* __restrict__ PY,
                      int kLen, int nsplit) {
    __shared__ float lds[8192];
    const int tid = threadIdx.x;

    if ((int)blockIdx.z < nsplit) {
        // ================= gram role =================
        const int bx = blockIdx.x, by = blockIdx.y, bz = blockIdx.z;
        if (by < bx) return;
        float* As = lds;            // [32][128]
        float* Bs = lds + 4096;     // [32][128]
        const int a0 = bx * 128, b0 = by * 128;
        float* __restrict__ Gp = Gout + (size_t)bz * GELEMS;
        const int tx = tid & 15;
        const int ty = tid >> 4;
        const int lr = tid >> 5;
        const int lc = (tid & 31) * 4;
        const bool aIn = (a0 + 128) <= 1024;
        const bool bIn = (b0 + 128) <= 1024;

        float acc[8][8];
#pragma unroll
        for (int m = 0; m < 8; ++m)
#pragma unroll
            for (int n = 0; n < 8; ++n) acc[m][n] = 0.0f;

        const int kBase = bz * kLen;
        for (int kc = 0; kc < kLen; kc += 32) {
#pragma unroll
            for (int rr = 0; rr < 4; ++rr) {
                const int r = lr + rr * 8;
                const int l = kBase + kc + r;
                if (aIn) {
                    *(float4*)&As[r * 128 + lc] = *(const float4*)&X0[(size_t)l * 1024 + a0 + lc];
                } else {
#pragma unroll
                    for (int k = 0; k < 4; ++k) {
                        const int col = a0 + lc + k;
                        As[r * 128 + lc + k] = (col < 1024) ? X0[(size_t)l * 1024 + col]
                                                            : (col == 1024 ? 1.0f : 0.0f);
                    }
                }
                if (bIn) {
                    *(float4*)&Bs[r * 128 + lc] = *(const float4*)&X0[(size_t)l * 1024 + b0 + lc];
                } else {
#pragma unroll
                    for (int k = 0; k < 4; ++k) {
                        const int col = b0 + lc + k;
                        Bs[r * 128 + lc + k] = (col < 1024) ? X0[(size_t)l * 1024 + col]
                                                            : (col == 1024 ? 1.0f : 0.0f);
                    }
                }
            }
            __syncthreads();
#pragma unroll 8
            for (int l = 0; l < 32; ++l) {
                float4 a01 = *(const float4*)&As[l * 128 + ty * 8];
                float4 a23 = *(const float4*)&As[l * 128 + ty * 8 + 4];
                float4 bA  = *(const float4*)&Bs[l * 128 + tx * 4];
                float4 bB  = *(const float4*)&Bs[l * 128 + 64 + tx * 4];
                float am[8] = {a01.x, a01.y, a01.z, a01.w, a23.x, a23.y, a23.z, a23.w};
                float bn[8] = {bA.x, bA.y, bA.z, bA.w, bB.x, bB.y, bB.z, bB.w};
#pragma unroll
                for (int m = 0; m < 8; ++m)
#pragma unroll
                    for (int n = 0; n < 8; ++n)
                        acc[m][n] += am[m] * bn[n];
            }
            __syncthreads();
        }

#pragma unroll
        for (int m = 0; m < 8; ++m) {
            const int a = a0 + ty * 8 + m;
            if (a >= NATOMS) continue;
            const int bAc = b0 + tx * 4;
            const int bBc = b0 + 64 + tx * 4;
            if (bAc < GSTRIDE) {
                *(float4*)&Gp[(size_t)a * GSTRIDE + bAc] =
                    make_float4(acc[m][0], acc[m][1], acc[m][2], acc[m][3]);
            }
            if (bBc < GSTRIDE) {
                *(float4*)&Gp[(size_t)a * GSTRIDE + bBc] =
                    make_float4(acc[m][4], acc[m][5], acc[m][6], acc[m][7]);
            }
        }
    } else {
        // ================= projy role =================
        const int pw = blockIdx.y * 9 + blockIdx.x;
        if (pw >= 68) return;
        const int a0 = (pw % 17) * 64;
        const int b0 = (pw / 17) * 16;
        float* Ds = lds;            // [32][64]
        float* Ys = lds + 2048;     // [32][17]
        const int tx = tid & 15;
        const int ty = tid >> 4;
        const bool aIn = (a0 + 64) <= 1024;

        float acc[4] = {0.0f, 0.0f, 0.0f, 0.0f};

        for (int kc = 0; kc < 1024; kc += 32) {
            {
                const int r  = tid >> 4;
                const int c4 = (tid & 15) * 4;
#pragma unroll
                for (int rr = 0; rr < 2; ++rr) {
                    const int row = r + rr * 16;
                    const int l = kc + row;
                    if (aIn) {
                        *(float4*)&Ds[row * 64 + c4] = *(const float4*)&X0[(size_t)l * 1024 + a0 + c4];
                    } else {
#pragma unroll
                        for (int k = 0; k < 4; ++k) {
                            const int col = a0 + c4 + k;
                            Ds[row * 64 + c4 + k] = (col < 1024) ? X0[(size_t)l * 1024 + col]
                                                                 : (col == 1024 ? 1.0f : 0.0f);
                        }
                    }
                }
            }
            for (int e = tid; e < 512; e += 256) {
                const int l = e & 31, bb = e >> 5;
                Ys[l * 17 + bb] = y[(size_t)(b0 + bb) * 1024 + kc + l];
            }
            __syncthreads();
#pragma unroll 8
            for (int l = 0; l < 32; ++l) {
                const float yv = Ys[l * 17 + ty];
                float4 dv = *(const float4*)&Ds[l * 64 + tx * 4];
                acc[0] += yv * dv.x; acc[1] += yv * dv.y;
                acc[2] += yv * dv.z; acc[3] += yv * dv.w;
            }
            __syncthreads();
        }
        const int a = a0 + tx * 4;
        if (a < GSTRIDE) {
            *(float4*)&PY[(size_t)(b0 + ty) * GSTRIDE + a] =
                make_float4(acc[0], acc[1], acc[2], acc[3]);
        }
    }
}

// ---------------------------------------------------------------------------
// combine: sum nsplit partials over upper tiles, write G[a][b] + mirror G[b][a]
// (exact symmetry), and diagG[a] = G[a][a].
// ---------------------------------------------------------------------------
__global__ __launch_bounds__(256)
void combine_kernel(const float* __restrict__ Gp, float* __restrict__ G,
                    float* __restrict__ diagG, int nsplit) {
    int tt = blockIdx.x, bx = 0;
    while (tt >= 9 - bx) { tt -= 9 - bx; ++bx; }
    const int by = bx + tt;
    const int yq = blockIdx.y;
    const int tid = threadIdx.x;
    for (int rep = 0; rep < 16; ++rep) {
        const int idx = yq * 4096 + rep * 256 + tid;
        const int r = idx >> 7, c = idx & 127;
        const int a = bx * 128 + r, b = by * 128 + c;
        if (a > 1024 || b > 1024) continue;
        float s = 0.0f;
        for (int z = 0; z < nsplit; ++z)
            s += Gp[(size_t)z * GELEMS + (size_t)a * GSTRIDE + b];
        G[(size_t)a * GSTRIDE + b] = s;
        G[(size_t)b * GSTRIDE + a] = s;
        if (a == b) diagG[a] = s;
    }
}

// ---------------------------------------------------------------------------
// omp: one wg/batch, 512 threads (8 waves), ONE barrier/iter.
// The ridge solve is fully replicated per wave with Ainv in REGISTERS
// (lane l holds row l as ainv[0..31]); wv/rhs/uvb are lane registers; uvb[j]
// broadcast via v_readlane. Eliminates the solve barrier and all Ainv/uvb/wv
// LDS traffic. Races: row-i staging vs other waves' solve reads of row i are
// benign (Ainv column i is exactly 0 at iter i); redV/redI double-buffered by
// parity; proj-update overshoot terms are 0 (uvb[j>i]=0 AND rows[j>i]=0; the
// j==i term uses only the in-flight registers, stage happens after -- R7).
// ---------------------------------------------------------------------------
__global__ __launch_bounds__(512)
void omp_kernel(const float* __restrict__ G, const float* __restrict__ PY,
                const float* __restrict__ diagG,
                int* __restrict__ idxOut, float* __restrict__ wOut) {
    __shared__ float rowsLds[NNZ][GSTRIDE];   // 133,120 B, zero-init
    __shared__ float pyLds[1040];
    __shared__ float diagLds[1040];
    __shared__ float redV[2][8];
    __shared__ int   redI[2][8];

    const int b = blockIdx.x, tid = threadIdx.x;
    const int lane = tid & 63, wid = tid >> 6;

    // ---- per-lane replicated solver state (registers)
    float ainv[32];
#pragma unroll
    for (int m = 0; m < 32; ++m) ainv[m] = 0.0f;
    float wvr = 0.0f, rhsr = 0.0f;
    int   myIdx = 0;
    float myW = 0.0f;

    // ---- init LDS
    {
        float4 z4 = make_float4(0.f, 0.f, 0.f, 0.f);
        float4* rz = (float4*)rowsLds;
        for (int u = tid; u < NNZ * GSTRIDE / 4; u += 512) rz[u] = z4;
        const float* pyg = PY + (size_t)b * GSTRIDE;
        for (int u = tid; u < 1040; u += 512) pyLds[u] = pyg[u];
        for (int u = tid; u < 1025; u += 512) diagLds[u] = diagG[u];
    }
    __syncthreads();

    // ---- registers: proj for atoms tid, tid+512 (+1024 on tid 511)
    float p0 = pyLds[tid], p1 = pyLds[tid + 512];
    float p2 = (tid == 511) ? pyLds[1024] : 0.0f;

    // ---- prologue argmax on |py| -> parity 0
    {
        float best = fabsf(p0); int bidx = tid;
        { float v = fabsf(p1); if (v > best) { best = v; bidx = tid + 512; } }
        if (tid == 511) { float v = fabsf(p2); if (v > best) { best = v; bidx = 1024; } }
        const float wmax = wave_max64(best);
        const unsigned long long mask = __ballot(best == wmax);
        const int fl = __ffsll((unsigned long long)mask) - 1;
        const int widx = __builtin_amdgcn_readlane(bidx, fl);
        if (lane == 0) { redV[0][wid] = wmax; redI[0][wid] = widx; }
    }
    __syncthreads();

    for (int i = 0; i < NNZ; ++i) {
        const int par = i & 1;

        // ---- winner, replicated identically on all threads (broadcast reads)
        float bv_ = redV[par][0]; int sel = redI[par][0];
#pragma unroll
        for (int q = 1; q < 8; ++q) {
            if (redV[par][q] > bv_ || (redV[par][q] == bv_ && redI[par][q] < sel)) {
                bv_ = redV[par][q]; sel = redI[par][q];
            }
        }
        const float pysel = pyLds[sel];

        // ---- issue coalesced G-row loads NOW (complete under the solve)
        float r0 = 0.f, r1 = 0.f, r2 = 0.f;
        const float* __restrict__ grow = G + (size_t)sel * GSTRIDE;
        if (i < NNZ - 1) {
            r0 = grow[tid];
            r1 = grow[tid + 512];
            if (tid == 511) r2 = grow[1024];
        }

        // ---- replicated solve (every wave, identical): u = Ainv * G[sel]col
        const float bvl = (lane < 32) ? rowsLds[lane][sel] : 0.0f;
        float u0 = 0.f, u1 = 0.f, u2 = 0.f, u3 = 0.f;
#pragma unroll
        for (int m = 0; m < 32; m += 4) {            // rows >= i are 0
            u0 = fmaf(ainv[m + 0], rowsLds[m + 0][sel], u0);
            u1 = fmaf(ainv[m + 1], rowsLds[m + 1][sel], u1);
            u2 = fmaf(ainv[m + 2], rowsLds[m + 2][sel], u2);
            u3 = fmaf(ainv[m + 3], rowsLds[m + 3][sel], u3);
        }
        const float uacc = (u0 + u1) + (u2 + u3);    // 0 for lanes with zero rows
        const float t = wave_sum64(bvl * uacc);
        const float s = wave_sum64(rhsr * uacc);
        const float dinv = 1.0f / (diagLds[sel] + REGL - t);
        const float beta = dinv * (pysel - s);
        const float uvb = (lane == i) ? -1.0f : uacc;   // lanes>=32: uacc==0
        // rank-1 register update (next iter's Ainv); col/row i handled by uvb
#pragma unroll
        for (int m = 0; m < 32; ++m)
            ainv[m] = fmaf(uvb * dinv, readlane_f(uvb, m), ainv[m]);
        wvr = (lane == i) ? beta : fmaf(-uacc, beta, wvr);
        rhsr = (lane == i) ? pysel : rhsr;
        if (tid == i) myIdx = sel;                       // register capture

        if (i == NNZ - 1) break;

        // ---- incremental proj update: p += beta * sum_{j<=i} uvb_j*rows[j]
        //      j=i term ONLY via registers; rowsLds[i][own slots] still 0.
        float z0 = -r0, z1 = -r1, z2 = -r2;
        for (int jb = 0; jb < NNZ; jb += 8) {
            if (jb >= i) break;
#pragma unroll
            for (int jj = 0; jj < 8; ++jj) {
                const int j = jb + jj;                   // j >= i terms are 0
                const float uj = readlane_f(uvb, j);
                z0 = fmaf(uj, rowsLds[j][tid],       z0);
                z1 = fmaf(uj, rowsLds[j][tid + 512], z1);
                if (tid == 511) z2 = fmaf(uj, rowsLds[j][1024], z2);
            }
        }
        p0 = fmaf(beta, z0, p0);
        p1 = fmaf(beta, z1, p1);
        if (tid == 511) p2 = fmaf(beta, z2, p2);

        // ---- stage row i (own slots; program-order after proj reads)
        rowsLds[i][tid]       = r0;
        rowsLds[i][tid + 512] = r1;
        if (tid == 511) rowsLds[i][1024] = r2;

        // ---- abs-argmax -> other parity
        {
            float best = fabsf(p0); int bidx = tid;
            { float v = fabsf(p1); if (v > best) { best = v; bidx = tid + 512; } }
            if (tid == 511) { float v = fabsf(p2); if (v > best) { best = v; bidx = 1024; } }
            const float wmax = wave_max64(best);
            const unsigned long long mask = __ballot(best == wmax);
            const int fl = __ffsll((unsigned long long)mask) - 1;
            const int widx = __builtin_amdgcn_readlane(bidx, fl);
            if (lane == 0) { redV[par ^ 1][wid] = wmax; redI[par ^ 1][wid] = widx; }
        }
        __syncthreads();                                 // the ONE barrier
    }

    // outputs live in registers of wave 0 (tid<32): wvr = w[tid], myIdx = sel[tid]
    if (tid < NNZ) {
        idxOut[b * NNZ + tid] = myIdx;
        wOut[b * NNZ + tid] = wvr;
    }
}

// ---------------------------------------------------------------------------
// recon (sparse): out[b][l] = sum_i X[b][l][widx_i]*wval_i + bias.
// Dup last-wins semantics preserved via dense scatter + gather-and-zero;
// atom 1024 (ones column) redirected into the bias.
// ---------------------------------------------------------------------------
__global__ __launch_bounds__(256)
void recon_kernel(const float* __restrict__ X, const int* __restrict__ idxIn,
                  const float* __restrict__ wIn, float* __restrict__ out) {
    __shared__ float Wd[1025];
    __shared__ float wval[NNZ];
    __shared__ int   widx[NNZ];
    __shared__ float biasS;
    const int b = blockIdx.x >> 2, chunk = blockIdx.x & 3;
    const int tid = threadIdx.x;
    for (int u = tid; u < 1025; u += 256) Wd[u] = 0.0f;
    __syncthreads();
    if (tid == 0) {
#pragma unroll
        for (int i = 0; i < NNZ; ++i) Wd[idxIn[b * NNZ + i]] = wIn[b * NNZ + i];
        float bias = 0.0f;
#pragma unroll
        for (int i = 0; i < NNZ; ++i) {
            const int gi = idxIn[b * NNZ + i];
            const float v = Wd[gi];
            Wd[gi] = 0.0f;                       // dup i reads 0 second time
            const bool isOnes = (gi == 1024);
            if (isOnes) bias += v;
            widx[i] = isOnes ? 0 : gi;
            wval[i] = isOnes ? 0.0f : v;
        }
        biasS = bias;
    }
    __syncthreads();
    const int l = chunk * 256 + tid;
    const float* __restrict__ xr = X + (size_t)b * 1024 * 1024 + (size_t)l * 1024;
    float a0 = biasS, a1 = 0.f, a2 = 0.f, a3 = 0.f;
#pragma unroll
    for (int i = 0; i < NNZ; i += 4) {
        a0 = fmaf(xr[widx[i + 0]], wval[i + 0], a0);
        a1 = fmaf(xr[widx[i + 1]], wval[i + 1], a1);
        a2 = fmaf(xr[widx[i + 2]], wval[i + 2], a2);
        a3 = fmaf(xr[widx[i + 3]], wval[i + 3], a3);
    }
    out[(size_t)b * 1024 + l] = (a0 + a1) + (a2 + a3);
}

// ---------------------------------------------------------------------------
extern "C" void kernel_launch(void* const* d_in, const int* in_sizes, int n_in,
                              void* d_out, int out_size, void* d_ws, size_t ws_size,
                              hipStream_t stream) {
    const float* X = (const float*)d_in[0];
    const float* y = (const float*)d_in[1];
    float* out = (float*)d_out;
    float* ws = (float*)d_ws;

    const size_t need4 = ((size_t)GELEMS * 5 + 64 * GSTRIDE + NBATCH * NNZ * 2 + 2048) * sizeof(float);
    const int nsplit = (ws_size >= need4) ? 4 : 1;
    const int kLen = 1024 / nsplit;

    float* Gp = ws;
    float* G  = ws + (size_t)GELEMS * nsplit;
    float* PY = G + (size_t)GELEMS;
    float* wOut = PY + (size_t)64 * GSTRIDE;
    int* idxOut = (int*)(wOut + NBATCH * NNZ);
    float* diagG = (float*)(idxOut + NBATCH * NNZ);

    gramprojy_kernel<<<dim3(9, 9, nsplit + 1), 256, 0, stream>>>(X, y, Gp, PY, kLen, nsplit);
    combine_kernel<<<dim3(45, 4), 256, 0, stream>>>(Gp, G, diagG, nsplit);
    omp_kernel<<<NBATCH, 512, 0, stream>>>(G, PY, diagG, idxOut, wOut);
    recon_kernel<<<NBATCH * 4, 256, 0, stream>>>(X, idxOut, wOut, out);
}

// Round 11
// 221.170 us; speedup vs baseline: 1.3645x; 1.0003x over previous
//
#include <hip/hip_runtime.h>
#include <math.h>

#define NATOMS   1025
#define GSTRIDE  1040               // padded row stride (floats)
#define GELEMS   (1025*GSTRIDE)
#define NNZ      32
#define NBATCH   64
#define REGL     0.0067153485f      // softplus(-5) in fp32

// DPP cross-lane helpers (VALU-latency, no LDS). old=0, bound_ctrl=false ->
// invalid source lanes contribute 0 (safe: max over non-negatives / sum).
#define DPPF(x, ctrl) __int_as_float(__builtin_amdgcn_update_dpp(0, __float_as_int(x), (ctrl), 0xF, 0xF, false))

__device__ __forceinline__ float wave_max64(float x) {
    x = fmaxf(x, DPPF(x, 0x111));   // row_shr:1
    x = fmaxf(x, DPPF(x, 0x112));   // row_shr:2
    x = fmaxf(x, DPPF(x, 0x114));   // row_shr:4
    x = fmaxf(x, DPPF(x, 0x118));   // row_shr:8
    x = fmaxf(x, DPPF(x, 0x142));   // row_bcast:15
    x = fmaxf(x, DPPF(x, 0x143));   // row_bcast:31
    return __int_as_float(__builtin_amdgcn_readlane(__float_as_int(x), 63));
}
__device__ __forceinline__ float wave_sum64(float x) {
    x += DPPF(x, 0x111);
    x += DPPF(x, 0x112);
    x += DPPF(x, 0x114);
    x += DPPF(x, 0x118);
    x += DPPF(x, 0x142);
    x += DPPF(x, 0x143);
    return __int_as_float(__builtin_amdgcn_readlane(__float_as_int(x), 63));
}
__device__ __forceinline__ float readlane_f(float x, int l) {
    return __int_as_float(__builtin_amdgcn_readlane(__float_as_int(x), l));
}

// ---------------------------------------------------------------------------
// fused gram+projy. blockIdx.z < nsplit: gram (triangular bx<=by, 128x128 tile,
// 8x8/thread, split-K partial). Each partial is written FULLY SYMMETRIC:
// upper tile normally + mirrored tile via register float4 stores (bx!=by).
// blockIdx.z == nsplit: projy (64-atom x 16-batch tile).
// ---------------------------------------------------------------------------
__global__ __launch_bounds__(256)
void gramprojy_kernel(const float* __restrict__ X0, const float* __restrict__ y,
                      float* __restrict__ Gout, float* __restrict__ PY,
                      int kLen, int nsplit) {
    __shared__ float lds[8192];
    const int tid = threadIdx.x;

    if ((int)blockIdx.z < nsplit) {
        // ================= gram role =================
        const int bx = blockIdx.x, by = blockIdx.y, bz = blockIdx.z;
        if (by < bx) return;
        float* As = lds;            // [32][128]
        float* Bs = lds + 4096;     // [32][128]
        const int a0 = bx * 128, b0 = by * 128;
        float* __restrict__ Gp = Gout + (size_t)bz * GELEMS;
        const int tx = tid & 15;
        const int ty = tid >> 4;
        const int lr = tid >> 5;
        const int lc = (tid & 31) * 4;
        const bool aIn = (a0 + 128) <= 1024;
        const bool bIn = (b0 + 128) <= 1024;

        float acc[8][8];
#pragma unroll
        for (int m = 0; m < 8; ++m)
#pragma unroll
            for (int n = 0; n < 8; ++n) acc[m][n] = 0.0f;

        const int kBase = bz * kLen;
        for (int kc = 0; kc < kLen; kc += 32) {
#pragma unroll
            for (int rr = 0; rr < 4; ++rr) {
                const int r = lr + rr * 8;
                const int l = kBase + kc + r;
                if (aIn) {
                    *(float4*)&As[r * 128 + lc] = *(const float4*)&X0[(size_t)l * 1024 + a0 + lc];
                } else {
#pragma unroll
                    for (int k = 0; k < 4; ++k) {
                        const int col = a0 + lc + k;
                        As[r * 128 + lc + k] = (col < 1024) ? X0[(size_t)l * 1024 + col]
                                                            : (col == 1024 ? 1.0f : 0.0f);
                    }
                }
                if (bIn) {
                    *(float4*)&Bs[r * 128 + lc] = *(const float4*)&X0[(size_t)l * 1024 + b0 + lc];
                } else {
#pragma unroll
                    for (int k = 0; k < 4; ++k) {
                        const int col = b0 + lc + k;
                        Bs[r * 128 + lc + k] = (col < 1024) ? X0[(size_t)l * 1024 + col]
                                                            : (col == 1024 ? 1.0f : 0.0f);
                    }
                }
            }
            __syncthreads();
#pragma unroll 8
            for (int l = 0; l < 32; ++l) {
                float4 a01 = *(const float4*)&As[l * 128 + ty * 8];
                float4 a23 = *(const float4*)&As[l * 128 + ty * 8 + 4];
                float4 bA  = *(const float4*)&Bs[l * 128 + tx * 4];
                float4 bB  = *(const float4*)&Bs[l * 128 + 64 + tx * 4];
                float am[8] = {a01.x, a01.y, a01.z, a01.w, a23.x, a23.y, a23.z, a23.w};
                float bn[8] = {bA.x, bA.y, bA.z, bA.w, bB.x, bB.y, bB.z, bB.w};
#pragma unroll
                for (int m = 0; m < 8; ++m)
#pragma unroll
                    for (int n = 0; n < 8; ++n)
                        acc[m][n] += am[m] * bn[n];
            }
            __syncthreads();
        }

        // upper tile write (rows a, cols b)
#pragma unroll
        for (int m = 0; m < 8; ++m) {
            const int a = a0 + ty * 8 + m;
            if (a >= NATOMS) continue;
            const int bAc = b0 + tx * 4;
            const int bBc = b0 + 64 + tx * 4;
            if (bAc < GSTRIDE) {
                *(float4*)&Gp[(size_t)a * GSTRIDE + bAc] =
                    make_float4(acc[m][0], acc[m][1], acc[m][2], acc[m][3]);
            }
            if (bBc < GSTRIDE) {
                *(float4*)&Gp[(size_t)a * GSTRIDE + bBc] =
                    make_float4(acc[m][4], acc[m][5], acc[m][6], acc[m][7]);
            }
        }
        // mirror write (rows b, cols a), register float4s; bx<by => a-range <1024
        if (bx != by) {
#pragma unroll
            for (int n = 0; n < 8; ++n) {
                const int colg = b0 + ((n < 4) ? (tx * 4 + n) : (64 + tx * 4 + (n - 4)));
                if (colg >= NATOMS) continue;
                const int a = a0 + ty * 8;
                *(float4*)&Gp[(size_t)colg * GSTRIDE + a] =
                    make_float4(acc[0][n], acc[1][n], acc[2][n], acc[3][n]);
                *(float4*)&Gp[(size_t)colg * GSTRIDE + a + 4] =
                    make_float4(acc[4][n], acc[5][n], acc[6][n], acc[7][n]);
            }
        }
    } else {
        // ================= projy role =================
        const int pw = blockIdx.y * 9 + blockIdx.x;
        if (pw >= 68) return;
        const int a0 = (pw % 17) * 64;
        const int b0 = (pw / 17) * 16;
        float* Ds = lds;            // [32][64]
        float* Ys = lds + 2048;     // [32][17]
        const int tx = tid & 15;
        const int ty = tid >> 4;
        const bool aIn = (a0 + 64) <= 1024;

        float acc[4] = {0.0f, 0.0f, 0.0f, 0.0f};

        for (int kc = 0; kc < 1024; kc += 32) {
            {
                const int r  = tid >> 4;
                const int c4 = (tid & 15) * 4;
#pragma unroll
                for (int rr = 0; rr < 2; ++rr) {
                    const int row = r + rr * 16;
                    const int l = kc + row;
                    if (aIn) {
                        *(float4*)&Ds[row * 64 + c4] = *(const float4*)&X0[(size_t)l * 1024 + a0 + c4];
                    } else {
#pragma unroll
                        for (int k = 0; k < 4; ++k) {
                            const int col = a0 + c4 + k;
                            Ds[row * 64 + c4 + k] = (col < 1024) ? X0[(size_t)l * 1024 + col]
                                                                 : (col == 1024 ? 1.0f : 0.0f);
                        }
                    }
                }
            }
            for (int e = tid; e < 512; e += 256) {
                const int l = e & 31, bb = e >> 5;
                Ys[l * 17 + bb] = y[(size_t)(b0 + bb) * 1024 + kc + l];
            }
            __syncthreads();
#pragma unroll 8
            for (int l = 0; l < 32; ++l) {
                const float yv = Ys[l * 17 + ty];
                float4 dv = *(const float4*)&Ds[l * 64 + tx * 4];
                acc[0] += yv * dv.x; acc[1] += yv * dv.y;
                acc[2] += yv * dv.z; acc[3] += yv * dv.w;
            }
            __syncthreads();
        }
        const int a = a0 + tx * 4;
        if (a < GSTRIDE) {
            *(float4*)&PY[(size_t)(b0 + ty) * GSTRIDE + a] =
                make_float4(acc[0], acc[1], acc[2], acc[3]);
        }
    }
}

// ---------------------------------------------------------------------------
// omp: one wg/batch, 512 threads (8 waves), ONE barrier/iter. Register Ainv
// (lane l = row l), replicated solve per wave. Stages G rows directly from
// the NS symmetric split-K partials: NS independent coalesced loads whose
// vmcnt wait is DEFERRED past the proj j-loop (z-accumulator excludes r; the
// j=i term applies as p += beta*z - beta*r at the end). rowsLds[i] staged
// after the proj reads (R7 lesson). diag built from partial diagonals at init.
// ---------------------------------------------------------------------------
template <int NS>
__global__ __launch_bounds__(512)
void omp_kernel(const float* __restrict__ Gp, const float* __restrict__ PY,
                int* __restrict__ idxOut, float* __restrict__ wOut) {
    __shared__ float rowsLds[NNZ][GSTRIDE];   // 133,120 B, zero-init
    __shared__ float pyLds[1040];
    __shared__ float diagLds[1040];
    __shared__ float redV[2][8];
    __shared__ int   redI[2][8];

    const int b = blockIdx.x, tid = threadIdx.x;
    const int lane = tid & 63, wid = tid >> 6;

    float ainv[32];
#pragma unroll
    for (int m = 0; m < 32; ++m) ainv[m] = 0.0f;
    float wvr = 0.0f, rhsr = 0.0f;
    int   myIdx = 0;

    // ---- init LDS
    {
        float4 z4 = make_float4(0.f, 0.f, 0.f, 0.f);
        float4* rz = (float4*)rowsLds;
        for (int u = tid; u < NNZ * GSTRIDE / 4; u += 512) rz[u] = z4;
        const float* pyg = PY + (size_t)b * GSTRIDE;
        for (int u = tid; u < 1040; u += 512) pyLds[u] = pyg[u];
        float d0 = 0.f, d1 = 0.f, d2 = 0.f;
#pragma unroll
        for (int z = 0; z < NS; ++z) {
            const float* gz = Gp + (size_t)z * GELEMS;
            d0 += gz[(size_t)tid * (GSTRIDE + 1)];
            d1 += gz[(size_t)(tid + 512) * (GSTRIDE + 1)];
            if (tid == 511) d2 += gz[(size_t)1024 * (GSTRIDE + 1)];
        }
        diagLds[tid] = d0;
        diagLds[tid + 512] = d1;
        if (tid == 511) diagLds[1024] = d2;
    }
    __syncthreads();

    float p0 = pyLds[tid], p1 = pyLds[tid + 512];
    float p2 = (tid == 511) ? pyLds[1024] : 0.0f;

    // ---- prologue argmax on |py| -> parity 0
    {
        float best = fabsf(p0); int bidx = tid;
        { float v = fabsf(p1); if (v > best) { best = v; bidx = tid + 512; } }
        if (tid == 511) { float v = fabsf(p2); if (v > best) { best = v; bidx = 1024; } }
        const float wmax = wave_max64(best);
        const unsigned long long mask = __ballot(best == wmax);
        const int fl = __ffsll((unsigned long long)mask) - 1;
        const int widx = __builtin_amdgcn_readlane(bidx, fl);
        if (lane == 0) { redV[0][wid] = wmax; redI[0][wid] = widx; }
    }
    __syncthreads();

    for (int i = 0; i < NNZ; ++i) {
        const int par = i & 1;

        float bv_ = redV[par][0]; int sel = redI[par][0];
#pragma unroll
        for (int q = 1; q < 8; ++q) {
            if (redV[par][q] > bv_ || (redV[par][q] == bv_ && redI[par][q] < sel)) {
                bv_ = redV[par][q]; sel = redI[par][q];
            }
        }
        const float pysel = pyLds[sel];

        // ---- issue NS independent coalesced row loads (waited on after j-loop)
        float rA0 = 0.f, rA1 = 0.f, rA2 = 0.f, rA3 = 0.f;
        float rB0 = 0.f, rB1 = 0.f, rB2 = 0.f, rB3 = 0.f;
        float rA4 = 0.f, rA5 = 0.f, rA6 = 0.f, rA7 = 0.f;
        float rB4 = 0.f, rB5 = 0.f, rB6 = 0.f, rB7 = 0.f;
        float rC = 0.f;
        if (i < NNZ - 1) {
            const size_t rowoff = (size_t)sel * GSTRIDE;
            const float* g0 = Gp + rowoff;
            rA0 = g0[tid];            rB0 = g0[tid + 512];
            if (NS > 1) { const float* g = g0 + (size_t)1 * GELEMS; rA1 = g[tid]; rB1 = g[tid + 512]; }
            if (NS > 2) { const float* g = g0 + (size_t)2 * GELEMS; rA2 = g[tid]; rB2 = g[tid + 512]; }
            if (NS > 3) { const float* g = g0 + (size_t)3 * GELEMS; rA3 = g[tid]; rB3 = g[tid + 512]; }
            if (NS > 4) { const float* g = g0 + (size_t)4 * GELEMS; rA4 = g[tid]; rB4 = g[tid + 512]; }
            if (NS > 5) { const float* g = g0 + (size_t)5 * GELEMS; rA5 = g[tid]; rB5 = g[tid + 512]; }
            if (NS > 6) { const float* g = g0 + (size_t)6 * GELEMS; rA6 = g[tid]; rB6 = g[tid + 512]; }
            if (NS > 7) { const float* g = g0 + (size_t)7 * GELEMS; rA7 = g[tid]; rB7 = g[tid + 512]; }
            if (tid == 511) {
#pragma unroll
                for (int z = 0; z < NS; ++z) rC += Gp[(size_t)z * GELEMS + rowoff + 1024];
            }
        }

        // ---- replicated solve (every wave identical)
        const float bvl = (lane < 32) ? rowsLds[lane][sel] : 0.0f;
        float u0 = 0.f, u1 = 0.f, u2 = 0.f, u3 = 0.f;
#pragma unroll
        for (int m = 0; m < 32; m += 4) {            // rows >= i are 0
            u0 = fmaf(ainv[m + 0], rowsLds[m + 0][sel], u0);
            u1 = fmaf(ainv[m + 1], rowsLds[m + 1][sel], u1);
            u2 = fmaf(ainv[m + 2], rowsLds[m + 2][sel], u2);
            u3 = fmaf(ainv[m + 3], rowsLds[m + 3][sel], u3);
        }
        const float uacc = (u0 + u1) + (u2 + u3);
        const float t = wave_sum64(bvl * uacc);
        const float s = wave_sum64(rhsr * uacc);
        const float dinv = 1.0f / (diagLds[sel] + REGL - t);
        const float beta = dinv * (pysel - s);
        const float uvb = (lane == i) ? -1.0f : uacc;
#pragma unroll
        for (int m = 0; m < 32; ++m)
            ainv[m] = fmaf(uvb * dinv, readlane_f(uvb, m), ainv[m]);
        wvr = (lane == i) ? beta : fmaf(-uacc, beta, wvr);
        rhsr = (lane == i) ? pysel : rhsr;
        if (tid == i) myIdx = sel;

        if (i == NNZ - 1) break;

        // ---- proj j-loop first (pure LDS/VALU; no dependence on the loads)
        float z0 = 0.f, z1 = 0.f, z2 = 0.f;
        for (int jb = 0; jb < NNZ; jb += 8) {
            if (jb >= i) break;
#pragma unroll
            for (int jj = 0; jj < 8; ++jj) {
                const int j = jb + jj;                   // j >= i terms are 0
                const float uj = readlane_f(uvb, j);
                z0 = fmaf(uj, rowsLds[j][tid],       z0);
                z1 = fmaf(uj, rowsLds[j][tid + 512], z1);
                if (tid == 511) z2 = fmaf(uj, rowsLds[j][1024], z2);
            }
        }
        // ---- NOW consume the loads: r = sum of partials (vmcnt waits here)
        const float r0 = ((rA0 + rA1) + (rA2 + rA3)) + ((rA4 + rA5) + (rA6 + rA7));
        const float r1 = ((rB0 + rB1) + (rB2 + rB3)) + ((rB4 + rB5) + (rB6 + rB7));
        p0 = fmaf(beta, z0, p0); p0 = fmaf(-beta, r0, p0);
        p1 = fmaf(beta, z1, p1); p1 = fmaf(-beta, r1, p1);
        if (tid == 511) { p2 = fmaf(beta, z2, p2); p2 = fmaf(-beta, rC, p2); }

        // ---- stage row i (own slots; program-order after proj reads)
        rowsLds[i][tid]       = r0;
        rowsLds[i][tid + 512] = r1;
        if (tid == 511) rowsLds[i][1024] = rC;

        // ---- abs-argmax -> other parity
        {
            float best = fabsf(p0); int bidx = tid;
            { float v = fabsf(p1); if (v > best) { best = v; bidx = tid + 512; } }
            if (tid == 511) { float v = fabsf(p2); if (v > best) { best = v; bidx = 1024; } }
            const float wmax = wave_max64(best);
            const unsigned long long mask = __ballot(best == wmax);
            const int fl = __ffsll((unsigned long long)mask) - 1;
            const int widx = __builtin_amdgcn_readlane(bidx, fl);
            if (lane == 0) { redV[par ^ 1][wid] = wmax; redI[par ^ 1][wid] = widx; }
        }
        __syncthreads();                                 // the ONE barrier
    }

    if (tid < NNZ) {
        idxOut[b * NNZ + tid] = myIdx;
        wOut[b * NNZ + tid] = wvr;
    }
}

// ---------------------------------------------------------------------------
// recon (sparse): out[b][l] = sum_i X[b][l][widx_i]*wval_i + bias.
// Dup last-wins semantics preserved via dense scatter + gather-and-zero;
// atom 1024 (ones column) redirected into the bias.
// ---------------------------------------------------------------------------
__global__ __launch_bounds__(256)
void recon_kernel(const float* __restrict__ X, const int* __restrict__ idxIn,
                  const float* __restrict__ wIn, float* __restrict__ out) {
    __shared__ float Wd[1025];
    __shared__ float wval[NNZ];
    __shared__ int   widx[NNZ];
    __shared__ float biasS;
    const int b = blockIdx.x >> 2, chunk = blockIdx.x & 3;
    const int tid = threadIdx.x;
    for (int u = tid; u < 1025; u += 256) Wd[u] = 0.0f;
    __syncthreads();
    if (tid == 0) {
#pragma unroll
        for (int i = 0; i < NNZ; ++i) Wd[idxIn[b * NNZ + i]] = wIn[b * NNZ + i];
        float bias = 0.0f;
#pragma unroll
        for (int i = 0; i < NNZ; ++i) {
            const int gi = idxIn[b * NNZ + i];
            const float v = Wd[gi];
            Wd[gi] = 0.0f;                       // dup i reads 0 second time
            const bool isOnes = (gi == 1024);
            if (isOnes) bias += v;
            widx[i] = isOnes ? 0 : gi;
            wval[i] = isOnes ? 0.0f : v;
        }
        biasS = bias;
    }
    __syncthreads();
    const int l = chunk * 256 + tid;
    const float* __restrict__ xr = X + (size_t)b * 1024 * 1024 + (size_t)l * 1024;
    float a0 = biasS, a1 = 0.f, a2 = 0.f, a3 = 0.f;
#pragma unroll
    for (int i = 0; i < NNZ; i += 4) {
        a0 = fmaf(xr[widx[i + 0]], wval[i + 0], a0);
        a1 = fmaf(xr[widx[i + 1]], wval[i + 1], a1);
        a2 = fmaf(xr[widx[i + 2]], wval[i + 2], a2);
        a3 = fmaf(xr[widx[i + 3]], wval[i + 3], a3);
    }
    out[(size_t)b * 1024 + l] = (a0 + a1) + (a2 + a3);
}

// ---------------------------------------------------------------------------
extern "C" void kernel_launch(void* const* d_in, const int* in_sizes, int n_in,
                              void* d_out, int out_size, void* d_ws, size_t ws_size,
                              hipStream_t stream) {
    const float* X = (const float*)d_in[0];
    const float* y = (const float*)d_in[1];
    float* out = (float*)d_out;
    float* ws = (float*)d_ws;

    const size_t fixed = (size_t)64 * GSTRIDE + NBATCH * NNZ * 2 + 64;
    const size_t need8 = ((size_t)GELEMS * 8 + fixed) * sizeof(float);
    const size_t need4 = ((size_t)GELEMS * 4 + fixed) * sizeof(float);
    const int nsplit = (ws_size >= need8) ? 8 : ((ws_size >= need4) ? 4 : 1);
    const int kLen = 1024 / nsplit;

    float* Gp = ws;
    float* PY = ws + (size_t)GELEMS * nsplit;
    float* wOut = PY + (size_t)64 * GSTRIDE;
    int* idxOut = (int*)(wOut + NBATCH * NNZ);

    gramprojy_kernel<<<dim3(9, 9, nsplit + 1), 256, 0, stream>>>(X, y, Gp, PY, kLen, nsplit);
    if (nsplit == 8)      omp_kernel<8><<<NBATCH, 512, 0, stream>>>(Gp, PY, idxOut, wOut);
    else if (nsplit == 4) omp_kernel<4><<<NBATCH, 512, 0, stream>>>(Gp, PY, idxOut, wOut);
    else                  omp_kernel<1><<<NBATCH, 512, 0, stream>>>(Gp, PY, idxOut, wOut);
    recon_kernel<<<NBATCH * 4, 256, 0, stream>>>(X, idxOut, wOut, out);
}

// Round 12
// 179.752 us; speedup vs baseline: 1.6789x; 1.2304x over previous
//
#include <hip/hip_runtime.h>
#include <math.h>

#define NATOMS   1025
#define GSTRIDE  1040               // padded row stride (floats)
#define GELEMS   (1025*GSTRIDE)
#define NNZ      32
#define NBATCH   64
#define REGL     0.0067153485f      // softplus(-5) in fp32

// DPP cross-lane helpers (VALU-latency, no LDS). old=0, bound_ctrl=false ->
// invalid source lanes contribute 0 (safe: max over non-negatives / sum).
#define DPPF(x, ctrl) __int_as_float(__builtin_amdgcn_update_dpp(0, __float_as_int(x), (ctrl), 0xF, 0xF, false))

__device__ __forceinline__ float wave_max64(float x) {
    x = fmaxf(x, DPPF(x, 0x111));   // row_shr:1
    x = fmaxf(x, DPPF(x, 0x112));   // row_shr:2
    x = fmaxf(x, DPPF(x, 0x114));   // row_shr:4
    x = fmaxf(x, DPPF(x, 0x118));   // row_shr:8
    x = fmaxf(x, DPPF(x, 0x142));   // row_bcast:15
    x = fmaxf(x, DPPF(x, 0x143));   // row_bcast:31
    return __int_as_float(__builtin_amdgcn_readlane(__float_as_int(x), 63));
}
__device__ __forceinline__ float wave_sum64(float x) {
    x += DPPF(x, 0x111);
    x += DPPF(x, 0x112);
    x += DPPF(x, 0x114);
    x += DPPF(x, 0x118);
    x += DPPF(x, 0x142);
    x += DPPF(x, 0x143);
    return __int_as_float(__builtin_amdgcn_readlane(__float_as_int(x), 63));
}
__device__ __forceinline__ float readlane_f(float x, int l) {
    return __int_as_float(__builtin_amdgcn_readlane(__float_as_int(x), l));
}

// ---------------------------------------------------------------------------
// fused gram+projy. blockIdx.z < nsplit: gram (triangular bx<=by, 128x128 tile,
// 8x8/thread, split-K partial). Each partial is written FULLY SYMMETRIC:
// upper tile normally + mirrored tile via register float4 stores (bx!=by).
// blockIdx.z == nsplit: projy (64-atom x 16-batch tile).
// ---------------------------------------------------------------------------
__global__ __launch_bounds__(256)
void gramprojy_kernel(const float* __restrict__ X0, const float* __restrict__ y,
                      float* __restrict__ Gout, float* __restrict__ PY,
                      int kLen, int nsplit) {
    __shared__ float lds[8192];
    const int tid = threadIdx.x;

    if ((int)blockIdx.z < nsplit) {
        // ================= gram role =================
        const int bx = blockIdx.x, by = blockIdx.y, bz = blockIdx.z;
        if (by < bx) return;
        float* As = lds;            // [32][128]
        float* Bs = lds + 4096;     // [32][128]
        const int a0 = bx * 128, b0 = by * 128;
        float* __restrict__ Gp = Gout + (size_t)bz * GELEMS;
        const int tx = tid & 15;
        const int ty = tid >> 4;
        const int lr = tid >> 5;
        const int lc = (tid & 31) * 4;
        const bool aIn = (a0 + 128) <= 1024;
        const bool bIn = (b0 + 128) <= 1024;

        float acc[8][8];
#pragma unroll
        for (int m = 0; m < 8; ++m)
#pragma unroll
            for (int n = 0; n < 8; ++n) acc[m][n] = 0.0f;

        const int kBase = bz * kLen;
        for (int kc = 0; kc < kLen; kc += 32) {
#pragma unroll
            for (int rr = 0; rr < 4; ++rr) {
                const int r = lr + rr * 8;
                const int l = kBase + kc + r;
                if (aIn) {
                    *(float4*)&As[r * 128 + lc] = *(const float4*)&X0[(size_t)l * 1024 + a0 + lc];
                } else {
#pragma unroll
                    for (int k = 0; k < 4; ++k) {
                        const int col = a0 + lc + k;
                        As[r * 128 + lc + k] = (col < 1024) ? X0[(size_t)l * 1024 + col]
                                                            : (col == 1024 ? 1.0f : 0.0f);
                    }
                }
                if (bIn) {
                    *(float4*)&Bs[r * 128 + lc] = *(const float4*)&X0[(size_t)l * 1024 + b0 + lc];
                } else {
#pragma unroll
                    for (int k = 0; k < 4; ++k) {
                        const int col = b0 + lc + k;
                        Bs[r * 128 + lc + k] = (col < 1024) ? X0[(size_t)l * 1024 + col]
                                                            : (col == 1024 ? 1.0f : 0.0f);
                    }
                }
            }
            __syncthreads();
#pragma unroll 8
            for (int l = 0; l < 32; ++l) {
                float4 a01 = *(const float4*)&As[l * 128 + ty * 8];
                float4 a23 = *(const float4*)&As[l * 128 + ty * 8 + 4];
                float4 bA  = *(const float4*)&Bs[l * 128 + tx * 4];
                float4 bB  = *(const float4*)&Bs[l * 128 + 64 + tx * 4];
                float am[8] = {a01.x, a01.y, a01.z, a01.w, a23.x, a23.y, a23.z, a23.w};
                float bn[8] = {bA.x, bA.y, bA.z, bA.w, bB.x, bB.y, bB.z, bB.w};
#pragma unroll
                for (int m = 0; m < 8; ++m)
#pragma unroll
                    for (int n = 0; n < 8; ++n)
                        acc[m][n] += am[m] * bn[n];
            }
            __syncthreads();
        }

        // upper tile write (rows a, cols b)
#pragma unroll
        for (int m = 0; m < 8; ++m) {
            const int a = a0 + ty * 8 + m;
            if (a >= NATOMS) continue;
            const int bAc = b0 + tx * 4;
            const int bBc = b0 + 64 + tx * 4;
            if (bAc < GSTRIDE) {
                *(float4*)&Gp[(size_t)a * GSTRIDE + bAc] =
                    make_float4(acc[m][0], acc[m][1], acc[m][2], acc[m][3]);
            }
            if (bBc < GSTRIDE) {
                *(float4*)&Gp[(size_t)a * GSTRIDE + bBc] =
                    make_float4(acc[m][4], acc[m][5], acc[m][6], acc[m][7]);
            }
        }
        // mirror write (rows b, cols a), register float4s; bx<by => a-range <1024
        if (bx != by) {
#pragma unroll
            for (int n = 0; n < 8; ++n) {
                const int colg = b0 + ((n < 4) ? (tx * 4 + n) : (64 + tx * 4 + (n - 4)));
                if (colg >= NATOMS) continue;
                const int a = a0 + ty * 8;
                *(float4*)&Gp[(size_t)colg * GSTRIDE + a] =
                    make_float4(acc[0][n], acc[1][n], acc[2][n], acc[3][n]);
                *(float4*)&Gp[(size_t)colg * GSTRIDE + a + 4] =
                    make_float4(acc[4][n], acc[5][n], acc[6][n], acc[7][n]);
            }
        }
    } else {
        // ================= projy role =================
        const int pw = blockIdx.y * 9 + blockIdx.x;
        if (pw >= 68) return;
        const int a0 = (pw % 17) * 64;
        const int b0 = (pw / 17) * 16;
        float* Ds = lds;            // [32][64]
        float* Ys = lds + 2048;     // [32][17]
        const int tx = tid & 15;
        const int ty = tid >> 4;
        const bool aIn = (a0 + 64) <= 1024;

        float acc[4] = {0.0f, 0.0f, 0.0f, 0.0f};

        for (int kc = 0; kc < 1024; kc += 32) {
            {
                const int r  = tid >> 4;
                const int c4 = (tid & 15) * 4;
#pragma unroll
                for (int rr = 0; rr < 2; ++rr) {
                    const int row = r + rr * 16;
                    const int l = kc + row;
                    if (aIn) {
                        *(float4*)&Ds[row * 64 + c4] = *(const float4*)&X0[(size_t)l * 1024 + a0 + c4];
                    } else {
#pragma unroll
                        for (int k = 0; k < 4; ++k) {
                            const int col = a0 + c4 + k;
                            Ds[row * 64 + c4 + k] = (col < 1024) ? X0[(size_t)l * 1024 + col]
                                                                 : (col == 1024 ? 1.0f : 0.0f);
                        }
                    }
                }
            }
            for (int e = tid; e < 512; e += 256) {
                const int l = e & 31, bb = e >> 5;
                Ys[l * 17 + bb] = y[(size_t)(b0 + bb) * 1024 + kc + l];
            }
            __syncthreads();
#pragma unroll 8
            for (int l = 0; l < 32; ++l) {
                const float yv = Ys[l * 17 + ty];
                float4 dv = *(const float4*)&Ds[l * 64 + tx * 4];
                acc[0] += yv * dv.x; acc[1] += yv * dv.y;
                acc[2] += yv * dv.z; acc[3] += yv * dv.w;
            }
            __syncthreads();
        }
        const int a = a0 + tx * 4;
        if (a < GSTRIDE) {
            *(float4*)&PY[(size_t)(b0 + ty) * GSTRIDE + a] =
                make_float4(acc[0], acc[1], acc[2], acc[3]);
        }
    }
}

// ---------------------------------------------------------------------------
// omp: one wg/batch, 512 threads (8 waves), 2 barriers/iter, ~9 KB LDS.
// All selected-row data lives in REGISTERS: thread tid keeps rr0[j]=G[sel_j][tid],
// rr1[j]=G[sel_j][tid+512] (main loop macro-stamped so all indices are static).
// Border b[m]=G[sel_m][sel] comes from the OWNER thread's registers (symmetry)
// via a 32-float bvec LDS buffer; atom 1024's row values live in row1024[].
// Garbage bvec[m>=i] is annihilated by ainv's structural zero rows/cols.
// Staging loads issue right after the winner; vmcnt consumed after the j-loop.
// ---------------------------------------------------------------------------
template <int NS>
__global__ __launch_bounds__(512)
void omp_kernel(const float* __restrict__ Gp, const float* __restrict__ PY,
                int* __restrict__ idxOut, float* __restrict__ wOut) {
    __shared__ float pyLds[1040];
    __shared__ float diagLds[1040];
    __shared__ float bvec[32];
    __shared__ float row1024[NNZ];
    __shared__ float redV[2][8];
    __shared__ int   redI[2][8];

    const int b = blockIdx.x, tid = threadIdx.x;
    const int lane = tid & 63, wid = tid >> 6;

    float rr0[NNZ], rr1[NNZ];     // my two atoms of every staged row
    float ainv[32];
#pragma unroll
    for (int m = 0; m < 32; ++m) { ainv[m] = 0.f; rr0[m] = 0.f; rr1[m] = 0.f; }
    float wvr = 0.f, rhsr = 0.f;
    int   myIdx = 0;

    // ---- init
    {
        const float* pyg = PY + (size_t)b * GSTRIDE;
        pyLds[tid] = pyg[tid];
        pyLds[tid + 512] = pyg[tid + 512];
        if (tid < 16) pyLds[1024 + tid] = pyg[1024 + tid];
        float d0 = 0.f, d1 = 0.f, d2 = 0.f;
#pragma unroll
        for (int z = 0; z < NS; ++z) {
            const float* gz = Gp + (size_t)z * GELEMS;
            d0 += gz[(size_t)tid * (GSTRIDE + 1)];
            d1 += gz[(size_t)(tid + 512) * (GSTRIDE + 1)];
            if (tid == 511) d2 += gz[(size_t)1024 * (GSTRIDE + 1)];
        }
        diagLds[tid] = d0;
        diagLds[tid + 512] = d1;
        if (tid == 511) diagLds[1024] = d2;
        if (tid < 32) { bvec[tid] = 0.f; row1024[tid] = 0.f; }
    }
    __syncthreads();

    float p0 = pyLds[tid], p1 = pyLds[tid + 512];
    float p2 = (tid == 511) ? pyLds[1024] : 0.f;

    // ---- prologue argmax on |py| -> parity 0
    {
        float best = fabsf(p0); int bidx = tid;
        { float v = fabsf(p1); if (v > best) { best = v; bidx = tid + 512; } }
        if (tid == 511) { float v = fabsf(p2); if (v > best) { best = v; bidx = 1024; } }
        const float wmax = wave_max64(best);
        const unsigned long long mask = __ballot(best == wmax);
        const int fl = __ffsll((unsigned long long)mask) - 1;
        const int widx = __builtin_amdgcn_readlane(bidx, fl);
        if (lane == 0) { redV[0][wid] = wmax; redI[0][wid] = widx; }
    }
    __syncthreads();

    // ================= macro-stamped main loop (static register indexing) ====
#define OMP_ITER(I)                                                            \
    {                                                                          \
        const int par = (I) & 1;                                               \
        float bv_ = redV[par][0]; int sel = redI[par][0];                      \
        _Pragma("unroll")                                                      \
        for (int q = 1; q < 8; ++q) {                                          \
            if (redV[par][q] > bv_ ||                                          \
                (redV[par][q] == bv_ && redI[par][q] < sel)) {                 \
                bv_ = redV[par][q]; sel = redI[par][q];                        \
            }                                                                  \
        }                                                                      \
        const float pysel = pyLds[sel];                                        \
        float rA0=0.f,rA1=0.f,rA2=0.f,rA3=0.f;                                 \
        float rB0=0.f,rB1=0.f,rB2=0.f,rB3=0.f,rC=0.f;                          \
        if ((I) < NNZ - 1) {                                                   \
            const size_t ro = (size_t)sel * GSTRIDE;                           \
            { const float* g = Gp + ro; rA0 = g[tid]; rB0 = g[tid + 512]; }    \
            if (NS > 1) { const float* g = Gp + ro + (size_t)1 * GELEMS;       \
                          rA1 = g[tid]; rB1 = g[tid + 512]; }                  \
            if (NS > 2) { const float* g = Gp + ro + (size_t)2 * GELEMS;       \
                          rA2 = g[tid]; rB2 = g[tid + 512]; }                  \
            if (NS > 3) { const float* g = Gp + ro + (size_t)3 * GELEMS;       \
                          rA3 = g[tid]; rB3 = g[tid + 512]; }                  \
            if (tid == 511) {                                                  \
                _Pragma("unroll")                                              \
                for (int z = 0; z < NS; ++z)                                   \
                    rC += Gp[(size_t)z * GELEMS + ro + 1024];                  \
            }                                                                  \
        }                                                                      \
        if (sel == 1024) {                                                     \
            if (tid < 32) bvec[tid] = row1024[tid];                            \
        } else if (tid == (sel & 511)) {                                       \
            if (sel >> 9) {                                                    \
                _Pragma("unroll")                                              \
                for (int m = 0; m < 32; ++m) bvec[m] = rr1[m];                 \
            } else {                                                           \
                _Pragma("unroll")                                              \
                for (int m = 0; m < 32; ++m) bvec[m] = rr0[m];                 \
            }                                                                  \
        }                                                                      \
        __syncthreads();                      /* bar1: bvec visible */         \
        const float bvl = (lane < 32) ? bvec[lane] : 0.f;                      \
        float u0 = 0.f, u1 = 0.f;                                              \
        _Pragma("unroll")                                                      \
        for (int m = 0; m < 32; m += 2) {                                      \
            u0 = fmaf(ainv[m],     bvec[m],     u0);                           \
            u1 = fmaf(ainv[m + 1], bvec[m + 1], u1);                           \
        }                                                                      \
        const float uacc = u0 + u1;                                            \
        const float t = wave_sum64(bvl * uacc);                                \
        const float s = wave_sum64(rhsr * uacc);                               \
        const float dinv = 1.0f / (diagLds[sel] + REGL - t);                   \
        const float beta = dinv * (pysel - s);                                 \
        const float uvb = (lane == (I)) ? -1.0f : uacc;                        \
        _Pragma("unroll")                                                      \
        for (int m = 0; m < 32; ++m)                                           \
            ainv[m] = fmaf(uvb * dinv, readlane_f(uvb, m), ainv[m]);           \
        wvr  = (lane == (I)) ? beta  : fmaf(-uacc, beta, wvr);                 \
        rhsr = (lane == (I)) ? pysel : rhsr;                                   \
        if (tid == (I)) myIdx = sel;                                           \
        if ((I) < NNZ - 1) {                                                   \
            float z0 = 0.f, z1 = 0.f, z2 = 0.f;                                \
            _Pragma("unroll")                                                  \
            for (int j = 0; j < NNZ - 1; ++j) {                                \
                if (j < (I)) {                                                 \
                    const float uj = readlane_f(uvb, j);                       \
                    z0 = fmaf(uj, rr0[j], z0);                                 \
                    z1 = fmaf(uj, rr1[j], z1);                                 \
                    if (tid == 511) z2 = fmaf(uj, row1024[j], z2);             \
                }                                                              \
            }                                                                  \
            const float r0 = (rA0 + rA1) + (rA2 + rA3);                        \
            const float r1 = (rB0 + rB1) + (rB2 + rB3);                        \
            p0 = fmaf(beta, z0, p0); p0 = fmaf(-beta, r0, p0);                 \
            p1 = fmaf(beta, z1, p1); p1 = fmaf(-beta, r1, p1);                 \
            if (tid == 511) { p2 = fmaf(beta, z2, p2);                         \
                              p2 = fmaf(-beta, rC, p2); }                      \
            rr0[(I)] = r0; rr1[(I)] = r1;                                      \
            if (tid == 511) row1024[(I)] = rC;                                 \
            float best = fabsf(p0); int bidx = tid;                            \
            { float v = fabsf(p1); if (v > best) { best = v; bidx = tid + 512; } } \
            if (tid == 511) { float v = fabsf(p2);                             \
                              if (v > best) { best = v; bidx = 1024; } }       \
            const float wmax = wave_max64(best);                               \
            const unsigned long long mask = __ballot(best == wmax);            \
            const int fl = __ffsll((unsigned long long)mask) - 1;              \
            const int widx = __builtin_amdgcn_readlane(bidx, fl);              \
            if (lane == 0) { redV[par ^ 1][wid] = wmax;                        \
                             redI[par ^ 1][wid] = widx; }                      \
            __syncthreads();                  /* bar2: redV + rows visible */  \
        }                                                                      \
    }

    OMP_ITER(0)  OMP_ITER(1)  OMP_ITER(2)  OMP_ITER(3)
    OMP_ITER(4)  OMP_ITER(5)  OMP_ITER(6)  OMP_ITER(7)
    OMP_ITER(8)  OMP_ITER(9)  OMP_ITER(10) OMP_ITER(11)
    OMP_ITER(12) OMP_ITER(13) OMP_ITER(14) OMP_ITER(15)
    OMP_ITER(16) OMP_ITER(17) OMP_ITER(18) OMP_ITER(19)
    OMP_ITER(20) OMP_ITER(21) OMP_ITER(22) OMP_ITER(23)
    OMP_ITER(24) OMP_ITER(25) OMP_ITER(26) OMP_ITER(27)
    OMP_ITER(28) OMP_ITER(29) OMP_ITER(30) OMP_ITER(31)
#undef OMP_ITER

    if (tid < NNZ) {
        idxOut[b * NNZ + tid] = myIdx;
        wOut[b * NNZ + tid] = wvr;
    }
}

// ---------------------------------------------------------------------------
// recon (sparse): out[b][l] = sum_i X[b][l][widx_i]*wval_i + bias.
// Dup last-wins semantics preserved via dense scatter + gather-and-zero;
// atom 1024 (ones column) redirected into the bias.
// ---------------------------------------------------------------------------
__global__ __launch_bounds__(256)
void recon_kernel(const float* __restrict__ X, const int* __restrict__ idxIn,
                  const float* __restrict__ wIn, float* __restrict__ out) {
    __shared__ float Wd[1025];
    __shared__ float wval[NNZ];
    __shared__ int   widx[NNZ];
    __shared__ float biasS;
    const int b = blockIdx.x >> 2, chunk = blockIdx.x & 3;
    const int tid = threadIdx.x;
    for (int u = tid; u < 1025; u += 256) Wd[u] = 0.0f;
    __syncthreads();
    if (tid == 0) {
#pragma unroll
        for (int i = 0; i < NNZ; ++i) Wd[idxIn[b * NNZ + i]] = wIn[b * NNZ + i];
        float bias = 0.0f;
#pragma unroll
        for (int i = 0; i < NNZ; ++i) {
            const int gi = idxIn[b * NNZ + i];
            const float v = Wd[gi];
            Wd[gi] = 0.0f;                       // dup i reads 0 second time
            const bool isOnes = (gi == 1024);
            if (isOnes) bias += v;
            widx[i] = isOnes ? 0 : gi;
            wval[i] = isOnes ? 0.0f : v;
        }
        biasS = bias;
    }
    __syncthreads();
    const int l = chunk * 256 + tid;
    const float* __restrict__ xr = X + (size_t)b * 1024 * 1024 + (size_t)l * 1024;
    float a0 = biasS, a1 = 0.f, a2 = 0.f, a3 = 0.f;
#pragma unroll
    for (int i = 0; i < NNZ; i += 4) {
        a0 = fmaf(xr[widx[i + 0]], wval[i + 0], a0);
        a1 = fmaf(xr[widx[i + 1]], wval[i + 1], a1);
        a2 = fmaf(xr[widx[i + 2]], wval[i + 2], a2);
        a3 = fmaf(xr[widx[i + 3]], wval[i + 3], a3);
    }
    out[(size_t)b * 1024 + l] = (a0 + a1) + (a2 + a3);
}

// ---------------------------------------------------------------------------
extern "C" void kernel_launch(void* const* d_in, const int* in_sizes, int n_in,
                              void* d_out, int out_size, void* d_ws, size_t ws_size,
                              hipStream_t stream) {
    const float* X = (const float*)d_in[0];
    const float* y = (const float*)d_in[1];
    float* out = (float*)d_out;
    float* ws = (float*)d_ws;

    const size_t fixed = (size_t)64 * GSTRIDE + NBATCH * NNZ * 2 + 64;
    const size_t need4 = ((size_t)GELEMS * 4 + fixed) * sizeof(float);
    const int nsplit = (ws_size >= need4) ? 4 : 1;
    const int kLen = 1024 / nsplit;

    float* Gp = ws;
    float* PY = ws + (size_t)GELEMS * nsplit;
    float* wOut = PY + (size_t)64 * GSTRIDE;
    int* idxOut = (int*)(wOut + NBATCH * NNZ);

    gramprojy_kernel<<<dim3(9, 9, nsplit + 1), 256, 0, stream>>>(X, y, Gp, PY, kLen, nsplit);
    if (nsplit == 4) omp_kernel<4><<<NBATCH, 512, 0, stream>>>(Gp, PY, idxOut, wOut);
    else             omp_kernel<1><<<NBATCH, 512, 0, stream>>>(Gp, PY, idxOut, wOut);
    recon_kernel<<<NBATCH * 4, 256, 0, stream>>>(X, idxOut, wOut, out);
}